// Round 4
// baseline (429.518 us; speedup 1.0000x reference)
//
#include <hip/hip_runtime.h>
#include <hip/hip_bf16.h>
#include <cstdint>

typedef __bf16 bf16;
typedef bf16 bf16x4 __attribute__((ext_vector_type(4)));
typedef bf16 bf16x8 __attribute__((ext_vector_type(8)));
typedef float f32x4 __attribute__((ext_vector_type(4)));

#define B_  2048
#define E_  512
#define H_  512
#define V_  50257
#define K1_ 1024
#define VPAD_ 50432   // 197*256

__device__ __forceinline__ void gload_lds16(const void* g, void* l) {
  __builtin_amdgcn_global_load_lds(
      (const __attribute__((address_space(1))) void*)g,
      (__attribute__((address_space(3))) void*)l, 16, 0, 0);
}

__device__ __forceinline__ float wave_sum(float v) {
#pragma unroll
  for (int o = 32; o > 0; o >>= 1) v += __shfl_xor(v, o, 64);
  return v;
}

// ---------------------------------------------------------------------------
// prep_big: gru_in bf16 [2048][1024]; wzrh bf16 [1536][1024];
//           wob bf16 [VPAD][512] (zero-padded rows V_..VPAD_)
// ---------------------------------------------------------------------------
__global__ __launch_bounds__(256) void prep_big_kernel(
    const float* __restrict__ hprev, const float* __restrict__ x,
    const float* __restrict__ Wz, const float* __restrict__ Wr,
    const float* __restrict__ Wh, const float* __restrict__ Wo,
    bf16* __restrict__ gin, bf16* __restrict__ wzrh, bf16* __restrict__ wob)
{
  const int i = blockIdx.x * 256 + threadIdx.x;
  constexpr int N1 = B_ * K1_ / 4;        // 524288
  constexpr int N2 = 1536 * K1_ / 4;      // 393216
  constexpr int N3 = V_ * 512 / 4;        // 6432896
  if (i < N1) {
    int e = i * 4;
    int m = e >> 10, k = e & 1023;
    const float* src = (k < 512) ? (hprev + (size_t)m * 512 + k)
                                 : (x + (size_t)m * 512 + (k - 512));
    f32x4 v = *reinterpret_cast<const f32x4*>(src);
    bf16x4 t; t[0]=(bf16)v[0]; t[1]=(bf16)v[1]; t[2]=(bf16)v[2]; t[3]=(bf16)v[3];
    *reinterpret_cast<bf16x4*>(gin + e) = t;
  } else if (i < N1 + N2) {
    int e = (i - N1) * 4;
    int which = e >> 19;
    int off = e & ((1 << 19) - 1);
    const float* W = (which == 0) ? Wz : (which == 1) ? Wr : Wh;
    f32x4 v = *reinterpret_cast<const f32x4*>(W + off);
    bf16x4 t; t[0]=(bf16)v[0]; t[1]=(bf16)v[1]; t[2]=(bf16)v[2]; t[3]=(bf16)v[3];
    *reinterpret_cast<bf16x4*>(wzrh + e) = t;
  } else if (i < N1 + N2 + N3) {
    size_t e = (size_t)(i - N1 - N2) * 4;
    f32x4 v = *reinterpret_cast<const f32x4*>(Wo + e);
    bf16x4 t; t[0]=(bf16)v[0]; t[1]=(bf16)v[1]; t[2]=(bf16)v[2]; t[3]=(bf16)v[3];
    *reinterpret_cast<bf16x4*>(wob + e) = t;
  } else {
    size_t e = (size_t)V_ * 512 + (size_t)(i - N1 - N2 - N3) * 4;
    bf16x4 t = {};
    *reinterpret_cast<bf16x4*>(wob + e) = t;
  }
}

// ---------------------------------------------------------------------------
// 2-phase pipelined bf16 GEMM (small GEMMs): C[M][N] = A[M][K] @ Bm[N][K]^T
// ---------------------------------------------------------------------------
__global__ __launch_bounds__(256) void gemm_bf16_nt(
    const bf16* __restrict__ A, const bf16* __restrict__ Bm,
    float* __restrict__ C, int M, int N, int K)
{
  __shared__ bf16 As[2][128 * 64];
  __shared__ bf16 Bs[2][128 * 64];
  const int tid = threadIdx.x;
  const int wid = tid >> 6, lane = tid & 63;
  const int bm = blockIdx.x, bn = blockIdx.y;
  const int wm = (wid >> 1) * 64, wn = (wid & 1) * 64;
  f32x4 acc[4][4] = {};
  const size_t a_row0 = (size_t)bm * 128;
  const size_t b_row0 = (size_t)bn * 128;

  int srow[4], scol[4];
#pragma unroll
  for (int i = 0; i < 4; ++i) {
    int idx = i * 256 + wid * 64 + lane;
    srow[i] = idx >> 3;
    scol[i] = ((idx & 7) ^ (srow[i] & 7)) << 3;
  }

  auto STAGE = [&](int buf, int k0) {
#pragma unroll
    for (int i = 0; i < 4; ++i) {
      int base = i * 256 + wid * 64;
      gload_lds16(A + (a_row0 + srow[i]) * K + (k0 + scol[i]), &As[buf][base * 8]);
      gload_lds16(Bm + (b_row0 + srow[i]) * K + (k0 + scol[i]), &Bs[buf][base * 8]);
    }
  };

  auto COMPUTE = [&](int buf) {
#pragma unroll
    for (int kk = 0; kk < 2; ++kk) {
      bf16x8 af[4], bb[4];
#pragma unroll
      for (int i = 0; i < 4; ++i) {
        int ra = wm + i * 16 + (lane & 15);
        int ca = (kk * 32 + (lane >> 4) * 8) ^ ((ra & 7) << 3);
        af[i] = *reinterpret_cast<const bf16x8*>(&As[buf][ra * 64 + ca]);
      }
#pragma unroll
      for (int j = 0; j < 4; ++j) {
        int rb = wn + j * 16 + (lane & 15);
        int cb = (kk * 32 + (lane >> 4) * 8) ^ ((rb & 7) << 3);
        bb[j] = *reinterpret_cast<const bf16x8*>(&Bs[buf][rb * 64 + cb]);
      }
      __builtin_amdgcn_s_setprio(1);
#pragma unroll
      for (int i = 0; i < 4; ++i)
#pragma unroll
        for (int j = 0; j < 4; ++j)
          acc[i][j] = __builtin_amdgcn_mfma_f32_16x16x32_bf16(af[i], bb[j], acc[i][j], 0, 0, 0);
      __builtin_amdgcn_s_setprio(0);
    }
  };

  STAGE(0, 0);
  asm volatile("s_waitcnt vmcnt(0)" ::: "memory");
  __syncthreads();
  const int nt = K >> 6;
  int cur = 0;
  for (int t = 0; t < nt - 1; ++t) {
    STAGE(cur ^ 1, (t + 1) << 6);
    COMPUTE(cur);
    asm volatile("s_waitcnt vmcnt(0)" ::: "memory");
    __syncthreads();
    cur ^= 1;
  }
  COMPUTE(cur);

  const int r0 = (lane >> 4) * 4, cc = lane & 15;
#pragma unroll
  for (int i = 0; i < 4; ++i)
#pragma unroll
    for (int j = 0; j < 4; ++j) {
      int n = bn * 128 + wn + j * 16 + cc;
#pragma unroll
      for (int q = 0; q < 4; ++q) {
        int mm = bm * 128 + wm + i * 16 + r0 + q;
        C[(size_t)mm * N + n] = acc[i][j][q];
      }
    }
}

// ---------------------------------------------------------------------------
// LN(+bias) + sigmoid for z and r; emit z (fp32) and cand_in bf16 [h_prev*r|x]
// ---------------------------------------------------------------------------
__global__ __launch_bounds__(256) void ln_zr_kernel(
    const float* __restrict__ zrp,
    const float* __restrict__ bz, const float* __restrict__ br,
    const float* __restrict__ gz, const float* __restrict__ bez,
    const float* __restrict__ gr, const float* __restrict__ ber,
    const float* __restrict__ hprev, const float* __restrict__ x,
    float* __restrict__ zbuf, bf16* __restrict__ cand)
{
  const int m = blockIdx.x, tid = threadIdx.x;
  const int wid = tid >> 6, lane = tid & 63;
  float zv[2], rv[2];
  float s0 = 0, s1 = 0, s2 = 0, s3 = 0;
#pragma unroll
  for (int e = 0; e < 2; ++e) {
    int n = tid + e * 256;
    float a = zrp[(size_t)m * 1024 + n] + bz[n];
    float b = zrp[(size_t)m * 1024 + 512 + n] + br[n];
    zv[e] = a; rv[e] = b;
    s0 += a; s1 += a * a; s2 += b; s3 += b * b;
  }
  s0 = wave_sum(s0); s1 = wave_sum(s1); s2 = wave_sum(s2); s3 = wave_sum(s3);
  __shared__ float red[4][4];
  if (lane == 0) { red[wid][0] = s0; red[wid][1] = s1; red[wid][2] = s2; red[wid][3] = s3; }
  __syncthreads();
  float zs = red[0][0] + red[1][0] + red[2][0] + red[3][0];
  float zq = red[0][1] + red[1][1] + red[2][1] + red[3][1];
  float rs = red[0][2] + red[1][2] + red[2][2] + red[3][2];
  float rq = red[0][3] + red[1][3] + red[2][3] + red[3][3];
  float zm = zs * (1.f / 512.f), zvr = zq * (1.f / 512.f) - zm * zm;
  float rm = rs * (1.f / 512.f), rvr = rq * (1.f / 512.f) - rm * rm;
  float zrs_ = rsqrtf(zvr + 1e-5f), rrs = rsqrtf(rvr + 1e-5f);
#pragma unroll
  for (int e = 0; e < 2; ++e) {
    int n = tid + e * 256;
    float zval = 1.f / (1.f + expf(-((zv[e] - zm) * zrs_ * gz[n] + bez[n])));
    float rval = 1.f / (1.f + expf(-((rv[e] - rm) * rrs * gr[n] + ber[n])));
    zbuf[(size_t)m * 512 + n] = zval;
    cand[(size_t)m * 1024 + n] = (bf16)(hprev[(size_t)m * 512 + n] * rval);
    cand[(size_t)m * 1024 + 512 + n] = (bf16)(x[(size_t)m * 512 + n]);
  }
}

// ---------------------------------------------------------------------------
// LN(+bias) + tanh for h_new; h_t = (1-z)*h_prev + z*h_new
// ---------------------------------------------------------------------------
__global__ __launch_bounds__(256) void ln_h_kernel(
    const float* __restrict__ hpre, const float* __restrict__ bh,
    const float* __restrict__ gh, const float* __restrict__ beh,
    const float* __restrict__ zbuf, const float* __restrict__ hprev,
    float* __restrict__ outh, bf16* __restrict__ htb)
{
  const int m = blockIdx.x, tid = threadIdx.x;
  const int wid = tid >> 6, lane = tid & 63;
  float v[2];
  float s0 = 0, s1 = 0;
#pragma unroll
  for (int e = 0; e < 2; ++e) {
    int n = tid + e * 256;
    float a = hpre[(size_t)m * 512 + n] + bh[n];
    v[e] = a; s0 += a; s1 += a * a;
  }
  s0 = wave_sum(s0); s1 = wave_sum(s1);
  __shared__ float red[4][2];
  if (lane == 0) { red[wid][0] = s0; red[wid][1] = s1; }
  __syncthreads();
  float ss = red[0][0] + red[1][0] + red[2][0] + red[3][0];
  float sq = red[0][1] + red[1][1] + red[2][1] + red[3][1];
  float mean = ss * (1.f / 512.f), var = sq * (1.f / 512.f) - mean * mean;
  float rstd = rsqrtf(var + 1e-5f);
#pragma unroll
  for (int e = 0; e < 2; ++e) {
    int n = tid + e * 256;
    float hn = tanhf((v[e] - mean) * rstd * gh[n] + beh[n]);
    float z = zbuf[(size_t)m * 512 + n];
    float ht = (1.f - z) * hprev[(size_t)m * 512 + n] + z * hn;
    outh[(size_t)m * 512 + n] = ht;
    htb[(size_t)m * 512 + n] = (bf16)ht;
  }
}

// ---------------------------------------------------------------------------
// big GEMM v3: 256x256 tile, 512 threads (8 waves, 2Mx4N), BK=32,
// 4-slot LDS ring, prefetch depth 3, counted vmcnt(8) — never 0 in loop.
// Y[2048][V_] = A[2048][512](bf16) @ wob[VPAD_][512](bf16)^T + bo
// grid 1576 = 8 XCD * 197, bm-inner logical order for Wo-panel L2 reuse.
// ---------------------------------------------------------------------------
__global__ __launch_bounds__(512, 2) void gemm_out256(
    const bf16* __restrict__ A, const bf16* __restrict__ Wb,
    const float* __restrict__ bo, float* __restrict__ Y)
{
  __shared__ bf16 lds[4][2][8192];   // [slot][A/B][256 rows x 32 k] = 128 KiB
  const int tid = threadIdx.x;
  const int wid = tid >> 6, lane = tid & 63;
  const int wr = wid >> 2, wc = wid & 3;     // 2 x 4 wave grid
  const int hw = blockIdx.x;
  const int logical = (hw & 7) * 197 + (hw >> 3);  // bijective XCD swizzle
  const int bm = logical & 7;                       // 8 M-tiles (inner)
  const int bn = logical >> 3;                      // 197 N-tiles
  const size_t a_row0 = (size_t)bm * 256;
  const size_t b_row0 = (size_t)bn * 256;
  f32x4 acc[8][4] = {};

  // staging: 1024 16B-chunks per operand-slot; 512 thr x 2; row = idx>>2,
  // chunk = idx&3, source chunk pre-swizzled by row&3 (involution, rule #21)
  auto STAGE = [&](int slot, int k0) {
#pragma unroll
    for (int i = 0; i < 2; ++i) {
      int base = i * 512 + wid * 64;        // wave-uniform chunk base
      int idx = base + lane;
      int row = idx >> 2;
      int csrc = ((idx & 3) ^ (row & 3)) << 3;   // element offset
      gload_lds16(A  + (a_row0 + row) * 512 + k0 + csrc, &lds[slot][0][base * 8]);
      gload_lds16(Wb + (b_row0 + row) * 512 + k0 + csrc, &lds[slot][1][base * 8]);
    }
  };

  auto COMPUTE = [&](int slot) {
    bf16x8 a[8], b[4];
#pragma unroll
    for (int i = 0; i < 8; ++i) {
      int r = wr * 128 + i * 16 + (lane & 15);
      int c = (((lane >> 4) ^ (r & 3))) << 3;
      a[i] = *reinterpret_cast<const bf16x8*>(&lds[slot][0][r * 32 + c]);
    }
#pragma unroll
    for (int j = 0; j < 4; ++j) {
      int r = wc * 64 + j * 16 + (lane & 15);
      int c = (((lane >> 4) ^ (r & 3))) << 3;
      b[j] = *reinterpret_cast<const bf16x8*>(&lds[slot][1][r * 32 + c]);
    }
    __builtin_amdgcn_s_setprio(1);
#pragma unroll
    for (int i = 0; i < 8; ++i)
#pragma unroll
      for (int j = 0; j < 4; ++j)
        acc[i][j] = __builtin_amdgcn_mfma_f32_16x16x32_bf16(a[i], b[j], acc[i][j], 0, 0, 0);
    __builtin_amdgcn_s_setprio(0);
  };

  // prologue: fill 3 slots ahead
  STAGE(0, 0); STAGE(1, 32); STAGE(2, 64);
  asm volatile("s_waitcnt vmcnt(8)" ::: "memory");   // slot 0 landed
  __builtin_amdgcn_s_barrier();

  // steady state: 16 K-slots total (K=512, BK=32)
#pragma unroll 1
  for (int s = 0; s < 13; ++s) {
    STAGE((s + 3) & 3, (s + 3) * 32);   // targets ring last read at phase s-1
    COMPUTE(s & 3);
    asm volatile("s_waitcnt vmcnt(8)" ::: "memory"); // slot s+1 landed
    __builtin_amdgcn_s_barrier();
  }
  // tail: slots 13,14,15 (no staging left)
  COMPUTE(1);
  asm volatile("s_waitcnt vmcnt(4)" ::: "memory");
  __builtin_amdgcn_s_barrier();
  COMPUTE(2);
  asm volatile("s_waitcnt vmcnt(0)" ::: "memory");
  __builtin_amdgcn_s_barrier();
  COMPUTE(3);

  // epilogue
  const int r0 = (lane >> 4) * 4, cc = lane & 15;
#pragma unroll
  for (int j = 0; j < 4; ++j) {
    int n = (int)b_row0 + wc * 64 + j * 16 + cc;
    if (n < V_) {
      float bia = bo[n];
#pragma unroll
      for (int i = 0; i < 8; ++i) {
#pragma unroll
        for (int q = 0; q < 4; ++q) {
          int mm = (int)a_row0 + wr * 128 + i * 16 + r0 + q;
          Y[(size_t)mm * V_ + n] = acc[i][j][q] + bia;
        }
      }
    }
  }
}

// ---------------------------------------------------------------------------
// fallback path (ws too small): fp32 Wo reg-staged GEMM + simple prep
// ---------------------------------------------------------------------------
__global__ __launch_bounds__(256) void gemm_out_kernel(
    const bf16* __restrict__ A, const float* __restrict__ Wo,
    const float* __restrict__ bo, float* __restrict__ Y)
{
  __shared__ bf16 As[128 * 64];
  __shared__ bf16 Bs[128 * 64];
  constexpr int K = 512;
  const int tid = threadIdx.x;
  const int wid = tid >> 6, lane = tid & 63;
  const int bm = blockIdx.x, bn = blockIdx.y;
  const int wm = (wid >> 1) * 64, wn = (wid & 1) * 64;
  f32x4 acc[4][4] = {};

  for (int k0 = 0; k0 < K; k0 += 64) {
#pragma unroll
    for (int i = 0; i < 4; ++i) {
      int base = i * 256 + wid * 64;
      int idx = base + lane;
      int row = idx >> 3, col = (idx & 7) << 3;
      gload_lds16(A + ((size_t)bm * 128 + row) * K + (k0 + col), &As[base * 8]);
    }
#pragma unroll
    for (int i = 0; i < 8; ++i) {
      int idx = i * 256 + tid;
      int row = idx >> 4;
      int c4 = (idx & 15) * 4;
      int n = bn * 128 + row;
      int nc = (n < V_) ? n : (V_ - 1);
      f32x4 v = *reinterpret_cast<const f32x4*>(Wo + (size_t)nc * K + k0 + c4);
      bf16x4 t; t[0]=(bf16)v[0]; t[1]=(bf16)v[1]; t[2]=(bf16)v[2]; t[3]=(bf16)v[3];
      *reinterpret_cast<bf16x4*>(&Bs[row * 64 + c4]) = t;
    }
    asm volatile("s_waitcnt vmcnt(0)" ::: "memory");
    __syncthreads();
#pragma unroll
    for (int kk = 0; kk < 2; ++kk) {
      bf16x8 af[4], bb[4];
#pragma unroll
      for (int i = 0; i < 4; ++i)
        af[i] = *reinterpret_cast<const bf16x8*>(
            &As[(wm + i * 16 + (lane & 15)) * 64 + kk * 32 + (lane >> 4) * 8]);
#pragma unroll
      for (int j = 0; j < 4; ++j)
        bb[j] = *reinterpret_cast<const bf16x8*>(
            &Bs[(wn + j * 16 + (lane & 15)) * 64 + kk * 32 + (lane >> 4) * 8]);
#pragma unroll
      for (int i = 0; i < 4; ++i)
#pragma unroll
        for (int j = 0; j < 4; ++j)
          acc[i][j] = __builtin_amdgcn_mfma_f32_16x16x32_bf16(af[i], bb[j], acc[i][j], 0, 0, 0);
    }
    __syncthreads();
  }

  const int r0 = (lane >> 4) * 4, cc = lane & 15;
#pragma unroll
  for (int i = 0; i < 4; ++i)
#pragma unroll
    for (int j = 0; j < 4; ++j) {
      int n = bn * 128 + wn + j * 16 + cc;
      if (n < V_) {
        float bia = bo[n];
#pragma unroll
        for (int q = 0; q < 4; ++q) {
          int mm = bm * 128 + wm + i * 16 + r0 + q;
          Y[(size_t)mm * V_ + n] = acc[i][j][q] + bia;
        }
      }
    }
}

__global__ __launch_bounds__(256) void prep_kernel(
    const float* __restrict__ hprev, const float* __restrict__ x,
    const float* __restrict__ Wz, const float* __restrict__ Wr,
    const float* __restrict__ Wh,
    bf16* __restrict__ gin, bf16* __restrict__ wzrh)
{
  const int i = blockIdx.x * 256 + threadIdx.x;
  constexpr int N1 = B_ * K1_ / 4;
  constexpr int N2 = 1536 * K1_ / 4;
  if (i < N1) {
    int e = i * 4;
    int m = e >> 10, k = e & 1023;
    const float* src = (k < 512) ? (hprev + (size_t)m * 512 + k)
                                 : (x + (size_t)m * 512 + (k - 512));
    f32x4 v = *reinterpret_cast<const f32x4*>(src);
    bf16x4 t; t[0]=(bf16)v[0]; t[1]=(bf16)v[1]; t[2]=(bf16)v[2]; t[3]=(bf16)v[3];
    *reinterpret_cast<bf16x4*>(gin + e) = t;
  } else if (i < N1 + N2) {
    int e = (i - N1) * 4;
    int which = e >> 19;
    int off = e & ((1 << 19) - 1);
    const float* W = (which == 0) ? Wz : (which == 1) ? Wr : Wh;
    f32x4 v = *reinterpret_cast<const f32x4*>(W + off);
    bf16x4 t; t[0]=(bf16)v[0]; t[1]=(bf16)v[1]; t[2]=(bf16)v[2]; t[3]=(bf16)v[3];
    *reinterpret_cast<bf16x4*>(wzrh + e) = t;
  }
}

// ---------------------------------------------------------------------------
extern "C" void kernel_launch(void* const* d_in, const int* in_sizes, int n_in,
                              void* d_out, int out_size, void* d_ws, size_t ws_size,
                              hipStream_t stream) {
  const float* x     = (const float*)d_in[0];
  const float* hprev = (const float*)d_in[1];
  const float* Wz    = (const float*)d_in[2];
  const float* bz    = (const float*)d_in[3];
  const float* gz    = (const float*)d_in[4];
  const float* bez   = (const float*)d_in[5];
  const float* Wr    = (const float*)d_in[6];
  const float* br    = (const float*)d_in[7];
  const float* gr    = (const float*)d_in[8];
  const float* ber   = (const float*)d_in[9];
  const float* Wh    = (const float*)d_in[10];
  const float* bh    = (const float*)d_in[11];
  const float* gh    = (const float*)d_in[12];
  const float* beh   = (const float*)d_in[13];
  const float* Wo    = (const float*)d_in[14];
  const float* bo    = (const float*)d_in[15];

  float* out_h = (float*)d_out;
  float* out_y = out_h + (size_t)B_ * H_;

  char* ws = (char*)d_ws;
  bf16*  gin  = (bf16*)(ws);                      // 4 MB   [2048][1024]
  bf16*  wzrh = (bf16*)(ws + ((size_t)4 << 20));  // 3 MB   [1536][1024]
  float* zrp  = (float*)(ws + ((size_t)7 << 20)); // 8 MB   [2048][1024]
  float* zbuf = (float*)(ws + ((size_t)15 << 20));// 4 MB   [2048][512]
  bf16*  cand = (bf16*)(ws + ((size_t)19 << 20)); // 4 MB   [2048][1024]
  float* hpre = (float*)(ws + ((size_t)23 << 20));// 4 MB   [2048][512]
  bf16*  htb  = (bf16*)(ws + ((size_t)27 << 20)); // 2 MB   [2048][512]
  bf16*  wob  = (bf16*)(ws + ((size_t)29 << 20)); // 51.6 MB [VPAD_][512]

  constexpr size_t NEED = ((size_t)29 << 20) + (size_t)VPAD_ * 512 * 2;

  if (ws_size >= NEED) {
    // items: 524288 + 393216 + 6432896 + 22400 = 7372800 -> 28800 blocks
    prep_big_kernel<<<28800, 256, 0, stream>>>(hprev, x, Wz, Wr, Wh, Wo, gin, wzrh, wob);
  } else {
    prep_kernel<<<3584, 256, 0, stream>>>(hprev, x, Wz, Wr, Wh, gin, wzrh);
  }

  gemm_bf16_nt<<<dim3(16, 8), 256, 0, stream>>>(gin, wzrh, zrp, B_, 1024, K1_);
  ln_zr_kernel<<<B_, 256, 0, stream>>>(zrp, bz, br, gz, bez, gr, ber, hprev, x, zbuf, cand);
  gemm_bf16_nt<<<dim3(16, 4), 256, 0, stream>>>(cand, wzrh + (size_t)1024 * 1024, hpre, B_, 512, K1_);
  ln_h_kernel<<<B_, 256, 0, stream>>>(hpre, bh, gh, beh, zbuf, hprev, out_h, htb);

  if (ws_size >= NEED) {
    gemm_out256<<<1576, 512, 0, stream>>>(htb, wob, bo, out_y);
  } else {
    gemm_out_kernel<<<dim3(16, 393), 256, 0, stream>>>(htb, Wo, bo, out_y);
  }
}

// Round 6
// 333.213 us; speedup vs baseline: 1.2890x; 1.2890x over previous
//
#include <hip/hip_runtime.h>
#include <hip/hip_bf16.h>
#include <cstdint>

typedef __bf16 bf16;
typedef bf16 bf16x4 __attribute__((ext_vector_type(4)));
typedef bf16 bf16x8 __attribute__((ext_vector_type(8)));
typedef float f32x4 __attribute__((ext_vector_type(4)));

#define B_  2048
#define E_  512
#define H_  512
#define V_  50257
#define K1_ 1024
#define VPAD_ 50432   // 197*256

__device__ __forceinline__ void gload_lds16(const void* g, void* l) {
  __builtin_amdgcn_global_load_lds(
      (const __attribute__((address_space(1))) void*)g,
      (__attribute__((address_space(3))) void*)l, 16, 0, 0);
}

__device__ __forceinline__ float wave_sum(float v) {
#pragma unroll
  for (int o = 32; o > 0; o >>= 1) v += __shfl_xor(v, o, 64);
  return v;
}

// ---------------------------------------------------------------------------
// prep_big: gru_in bf16 [2048][1024]; wzrh bf16 [1536][1024];
//           wob bf16 [VPAD][512] (zero-padded rows V_..VPAD_)
// ---------------------------------------------------------------------------
__global__ __launch_bounds__(256) void prep_big_kernel(
    const float* __restrict__ hprev, const float* __restrict__ x,
    const float* __restrict__ Wz, const float* __restrict__ Wr,
    const float* __restrict__ Wh, const float* __restrict__ Wo,
    bf16* __restrict__ gin, bf16* __restrict__ wzrh, bf16* __restrict__ wob)
{
  const int i = blockIdx.x * 256 + threadIdx.x;
  constexpr int N1 = B_ * K1_ / 4;        // 524288
  constexpr int N2 = 1536 * K1_ / 4;      // 393216
  constexpr int N3 = V_ * 512 / 4;        // 6432896
  if (i < N1) {
    int e = i * 4;
    int m = e >> 10, k = e & 1023;
    const float* src = (k < 512) ? (hprev + (size_t)m * 512 + k)
                                 : (x + (size_t)m * 512 + (k - 512));
    f32x4 v = *reinterpret_cast<const f32x4*>(src);
    bf16x4 t; t[0]=(bf16)v[0]; t[1]=(bf16)v[1]; t[2]=(bf16)v[2]; t[3]=(bf16)v[3];
    *reinterpret_cast<bf16x4*>(gin + e) = t;
  } else if (i < N1 + N2) {
    int e = (i - N1) * 4;
    int which = e >> 19;
    int off = e & ((1 << 19) - 1);
    const float* W = (which == 0) ? Wz : (which == 1) ? Wr : Wh;
    f32x4 v = *reinterpret_cast<const f32x4*>(W + off);
    bf16x4 t; t[0]=(bf16)v[0]; t[1]=(bf16)v[1]; t[2]=(bf16)v[2]; t[3]=(bf16)v[3];
    *reinterpret_cast<bf16x4*>(wzrh + e) = t;
  } else if (i < N1 + N2 + N3) {
    size_t e = (size_t)(i - N1 - N2) * 4;
    f32x4 v = *reinterpret_cast<const f32x4*>(Wo + e);
    bf16x4 t; t[0]=(bf16)v[0]; t[1]=(bf16)v[1]; t[2]=(bf16)v[2]; t[3]=(bf16)v[3];
    *reinterpret_cast<bf16x4*>(wob + e) = t;
  } else {
    size_t e = (size_t)V_ * 512 + (size_t)(i - N1 - N2 - N3) * 4;
    bf16x4 t = {};
    *reinterpret_cast<bf16x4*>(wob + e) = t;
  }
}

// ---------------------------------------------------------------------------
// 2-phase pipelined bf16 GEMM (small GEMMs): C[M][N] = A[M][K] @ Bm[N][K]^T
// ---------------------------------------------------------------------------
__global__ __launch_bounds__(256) void gemm_bf16_nt(
    const bf16* __restrict__ A, const bf16* __restrict__ Bm,
    float* __restrict__ C, int M, int N, int K)
{
  __shared__ bf16 As[2][128 * 64];
  __shared__ bf16 Bs[2][128 * 64];
  const int tid = threadIdx.x;
  const int wid = tid >> 6, lane = tid & 63;
  const int bm = blockIdx.x, bn = blockIdx.y;
  const int wm = (wid >> 1) * 64, wn = (wid & 1) * 64;
  f32x4 acc[4][4] = {};
  const size_t a_row0 = (size_t)bm * 128;
  const size_t b_row0 = (size_t)bn * 128;

  int srow[4], scol[4];
#pragma unroll
  for (int i = 0; i < 4; ++i) {
    int idx = i * 256 + wid * 64 + lane;
    srow[i] = idx >> 3;
    scol[i] = ((idx & 7) ^ (srow[i] & 7)) << 3;
  }

  auto STAGE = [&](int buf, int k0) {
#pragma unroll
    for (int i = 0; i < 4; ++i) {
      int base = i * 256 + wid * 64;
      gload_lds16(A + (a_row0 + srow[i]) * K + (k0 + scol[i]), &As[buf][base * 8]);
      gload_lds16(Bm + (b_row0 + srow[i]) * K + (k0 + scol[i]), &Bs[buf][base * 8]);
    }
  };

  auto COMPUTE = [&](int buf) {
#pragma unroll
    for (int kk = 0; kk < 2; ++kk) {
      bf16x8 af[4], bb[4];
#pragma unroll
      for (int i = 0; i < 4; ++i) {
        int ra = wm + i * 16 + (lane & 15);
        int ca = (kk * 32 + (lane >> 4) * 8) ^ ((ra & 7) << 3);
        af[i] = *reinterpret_cast<const bf16x8*>(&As[buf][ra * 64 + ca]);
      }
#pragma unroll
      for (int j = 0; j < 4; ++j) {
        int rb = wn + j * 16 + (lane & 15);
        int cb = (kk * 32 + (lane >> 4) * 8) ^ ((rb & 7) << 3);
        bb[j] = *reinterpret_cast<const bf16x8*>(&Bs[buf][rb * 64 + cb]);
      }
      __builtin_amdgcn_s_setprio(1);
#pragma unroll
      for (int i = 0; i < 4; ++i)
#pragma unroll
        for (int j = 0; j < 4; ++j)
          acc[i][j] = __builtin_amdgcn_mfma_f32_16x16x32_bf16(af[i], bb[j], acc[i][j], 0, 0, 0);
      __builtin_amdgcn_s_setprio(0);
    }
  };

  STAGE(0, 0);
  asm volatile("s_waitcnt vmcnt(0)" ::: "memory");
  __syncthreads();
  const int nt = K >> 6;
  int cur = 0;
  for (int t = 0; t < nt - 1; ++t) {
    STAGE(cur ^ 1, (t + 1) << 6);
    COMPUTE(cur);
    asm volatile("s_waitcnt vmcnt(0)" ::: "memory");
    __syncthreads();
    cur ^= 1;
  }
  COMPUTE(cur);

  const int r0 = (lane >> 4) * 4, cc = lane & 15;
#pragma unroll
  for (int i = 0; i < 4; ++i)
#pragma unroll
    for (int j = 0; j < 4; ++j) {
      int n = bn * 128 + wn + j * 16 + cc;
#pragma unroll
      for (int q = 0; q < 4; ++q) {
        int mm = bm * 128 + wm + i * 16 + r0 + q;
        C[(size_t)mm * N + n] = acc[i][j][q];
      }
    }
}

// ---------------------------------------------------------------------------
// LN(+bias) + sigmoid for z and r; emit z (fp32) and cand_in bf16 [h_prev*r|x]
// ---------------------------------------------------------------------------
__global__ __launch_bounds__(256) void ln_zr_kernel(
    const float* __restrict__ zrp,
    const float* __restrict__ bz, const float* __restrict__ br,
    const float* __restrict__ gz, const float* __restrict__ bez,
    const float* __restrict__ gr, const float* __restrict__ ber,
    const float* __restrict__ hprev, const float* __restrict__ x,
    float* __restrict__ zbuf, bf16* __restrict__ cand)
{
  const int m = blockIdx.x, tid = threadIdx.x;
  const int wid = tid >> 6, lane = tid & 63;
  float zv[2], rv[2];
  float s0 = 0, s1 = 0, s2 = 0, s3 = 0;
#pragma unroll
  for (int e = 0; e < 2; ++e) {
    int n = tid + e * 256;
    float a = zrp[(size_t)m * 1024 + n] + bz[n];
    float b = zrp[(size_t)m * 1024 + 512 + n] + br[n];
    zv[e] = a; rv[e] = b;
    s0 += a; s1 += a * a; s2 += b; s3 += b * b;
  }
  s0 = wave_sum(s0); s1 = wave_sum(s1); s2 = wave_sum(s2); s3 = wave_sum(s3);
  __shared__ float red[4][4];
  if (lane == 0) { red[wid][0] = s0; red[wid][1] = s1; red[wid][2] = s2; red[wid][3] = s3; }
  __syncthreads();
  float zs = red[0][0] + red[1][0] + red[2][0] + red[3][0];
  float zq = red[0][1] + red[1][1] + red[2][1] + red[3][1];
  float rs = red[0][2] + red[1][2] + red[2][2] + red[3][2];
  float rq = red[0][3] + red[1][3] + red[2][3] + red[3][3];
  float zm = zs * (1.f / 512.f), zvr = zq * (1.f / 512.f) - zm * zm;
  float rm = rs * (1.f / 512.f), rvr = rq * (1.f / 512.f) - rm * rm;
  float zrs_ = rsqrtf(zvr + 1e-5f), rrs = rsqrtf(rvr + 1e-5f);
#pragma unroll
  for (int e = 0; e < 2; ++e) {
    int n = tid + e * 256;
    float zval = 1.f / (1.f + expf(-((zv[e] - zm) * zrs_ * gz[n] + bez[n])));
    float rval = 1.f / (1.f + expf(-((rv[e] - rm) * rrs * gr[n] + ber[n])));
    zbuf[(size_t)m * 512 + n] = zval;
    cand[(size_t)m * 1024 + n] = (bf16)(hprev[(size_t)m * 512 + n] * rval);
    cand[(size_t)m * 1024 + 512 + n] = (bf16)(x[(size_t)m * 512 + n]);
  }
}

// ---------------------------------------------------------------------------
// LN(+bias) + tanh for h_new; h_t = (1-z)*h_prev + z*h_new
// ---------------------------------------------------------------------------
__global__ __launch_bounds__(256) void ln_h_kernel(
    const float* __restrict__ hpre, const float* __restrict__ bh,
    const float* __restrict__ gh, const float* __restrict__ beh,
    const float* __restrict__ zbuf, const float* __restrict__ hprev,
    float* __restrict__ outh, bf16* __restrict__ htb)
{
  const int m = blockIdx.x, tid = threadIdx.x;
  const int wid = tid >> 6, lane = tid & 63;
  float v[2];
  float s0 = 0, s1 = 0;
#pragma unroll
  for (int e = 0; e < 2; ++e) {
    int n = tid + e * 256;
    float a = hpre[(size_t)m * 512 + n] + bh[n];
    v[e] = a; s0 += a; s1 += a * a;
  }
  s0 = wave_sum(s0); s1 = wave_sum(s1);
  __shared__ float red[4][2];
  if (lane == 0) { red[wid][0] = s0; red[wid][1] = s1; }
  __syncthreads();
  float ss = red[0][0] + red[1][0] + red[2][0] + red[3][0];
  float sq = red[0][1] + red[1][1] + red[2][1] + red[3][1];
  float mean = ss * (1.f / 512.f), var = sq * (1.f / 512.f) - mean * mean;
  float rstd = rsqrtf(var + 1e-5f);
#pragma unroll
  for (int e = 0; e < 2; ++e) {
    int n = tid + e * 256;
    float hn = tanhf((v[e] - mean) * rstd * gh[n] + beh[n]);
    float z = zbuf[(size_t)m * 512 + n];
    float ht = (1.f - z) * hprev[(size_t)m * 512 + n] + z * hn;
    outh[(size_t)m * 512 + n] = ht;
    htb[(size_t)m * 512 + n] = (bf16)ht;
  }
}

// ---------------------------------------------------------------------------
// big GEMM v4b: 256x256 tile, BK=64, 2-tile LDS dbuf, 4 phases/tile.
// Phase = {<=12 ds_read_b128 | barrier | setprio+16 MFMA | 4 global_load_lds}.
// Each LDS fragment read ONCE per tile. vmcnt(0) only at tile end (issued
// 2-3 phases after the loads). chunk^=(row&7) swizzle, conflict-free
// (round-3 HW counter: 0 conflicts with this exact mapping).
// FIX vs v4: K-chunk index is kk*4 + (lane>>4)  [was kk*2 — wrong columns]
// ---------------------------------------------------------------------------
__global__ __launch_bounds__(512, 2) void gemm_out256(
    const bf16* __restrict__ A, const bf16* __restrict__ Wb,
    const float* __restrict__ bo, float* __restrict__ Y)
{
  __shared__ bf16 sm[2][2][256 * 64];   // [buf][op][row*64+col] = 128 KiB
  const int tid = threadIdx.x;
  const int wid = tid >> 6, lane = tid & 63;
  const int wr = wid >> 2, wc = wid & 3;            // 2M x 4N waves
  const int hw = blockIdx.x;
  const int logical = (hw & 7) * 197 + (hw >> 3);   // bijective XCD swizzle
  const int bm = logical & 7;                        // bm-inner: panel locality
  const int bn = logical >> 3;
  const size_t a_row0 = (size_t)bm * 256;
  const size_t b_row0 = (size_t)bn * 256;
  f32x4 acc[8][4] = {};

  auto STAGE = [&](int buf, int op, int kt) {       // one operand tile: 4 loads
    const bf16* src = op ? Wb : A;
    const size_t r0 = op ? b_row0 : a_row0;
    const int k0 = kt << 6;
#pragma unroll
    for (int s = 0; s < 4; ++s) {
      int idx = s * 512 + tid;
      int row = idx >> 3;
      int ch = ((idx & 7) ^ (row & 7)) << 3;        // pre-swizzled source
      gload_lds16(src + (r0 + row) * 512 + k0 + ch,
                  &sm[buf][op][(s * 512 + (tid & ~63)) * 8]);
    }
  };

  // prologue: stage tile 0 fully
  STAGE(0, 0, 0); STAGE(0, 1, 0);
  asm volatile("s_waitcnt vmcnt(0)" ::: "memory");
  __builtin_amdgcn_s_barrier();

#pragma unroll 1
  for (int t = 0; t < 8; ++t) {
    const int c = t & 1;
    bf16x8 a[8][2], b[4][2];

    auto rdA = [&](int i, int kk) -> bf16x8 {
      int r = wr * 128 + i * 16 + (lane & 15);
      int ch = ((kk * 4 + (lane >> 4)) ^ (r & 7)) << 3;   // FIXED: kk*4
      return *reinterpret_cast<const bf16x8*>(&sm[c][0][r * 64 + ch]);
    };
    auto rdB = [&](int j, int kk) -> bf16x8 {
      int r = wc * 64 + j * 16 + (lane & 15);
      int ch = ((kk * 4 + (lane >> 4)) ^ (r & 7)) << 3;   // FIXED: kk*4
      return *reinterpret_cast<const bf16x8*>(&sm[c][1][r * 64 + ch]);
    };

    // ---- phase 0: read a[0..3],b[0..1]; MFMA a[0..3]xb[0..1]; stage A(t+1)
#pragma unroll
    for (int i = 0; i < 4; ++i) { a[i][0] = rdA(i, 0); a[i][1] = rdA(i, 1); }
#pragma unroll
    for (int j = 0; j < 2; ++j) { b[j][0] = rdB(j, 0); b[j][1] = rdB(j, 1); }
    __builtin_amdgcn_s_barrier();
    __builtin_amdgcn_s_setprio(1);
#pragma unroll
    for (int i = 0; i < 4; ++i)
#pragma unroll
      for (int j = 0; j < 2; ++j)
#pragma unroll
        for (int kk = 0; kk < 2; ++kk)
          acc[i][j] = __builtin_amdgcn_mfma_f32_16x16x32_bf16(a[i][kk], b[j][kk], acc[i][j], 0, 0, 0);
    __builtin_amdgcn_s_setprio(0);
    if (t < 7) STAGE(c ^ 1, 0, t + 1);

    // ---- phase 1: read a[4..7],b[2..3]; MFMA a[4..7]xb[0..1]; stage B(t+1)
#pragma unroll
    for (int i = 4; i < 8; ++i) { a[i][0] = rdA(i, 0); a[i][1] = rdA(i, 1); }
#pragma unroll
    for (int j = 2; j < 4; ++j) { b[j][0] = rdB(j, 0); b[j][1] = rdB(j, 1); }
    __builtin_amdgcn_s_barrier();
    __builtin_amdgcn_s_setprio(1);
#pragma unroll
    for (int i = 4; i < 8; ++i)
#pragma unroll
      for (int j = 0; j < 2; ++j)
#pragma unroll
        for (int kk = 0; kk < 2; ++kk)
          acc[i][j] = __builtin_amdgcn_mfma_f32_16x16x32_bf16(a[i][kk], b[j][kk], acc[i][j], 0, 0, 0);
    __builtin_amdgcn_s_setprio(0);
    if (t < 7) STAGE(c ^ 1, 1, t + 1);

    // ---- phase 2: MFMA a[0..3]xb[2..3]
    __builtin_amdgcn_s_barrier();
    __builtin_amdgcn_s_setprio(1);
#pragma unroll
    for (int i = 0; i < 4; ++i)
#pragma unroll
      for (int j = 2; j < 4; ++j)
#pragma unroll
        for (int kk = 0; kk < 2; ++kk)
          acc[i][j] = __builtin_amdgcn_mfma_f32_16x16x32_bf16(a[i][kk], b[j][kk], acc[i][j], 0, 0, 0);
    __builtin_amdgcn_s_setprio(0);

    // ---- phase 3: MFMA a[4..7]xb[2..3]; tile-end wait
    __builtin_amdgcn_s_barrier();
    __builtin_amdgcn_s_setprio(1);
#pragma unroll
    for (int i = 4; i < 8; ++i)
#pragma unroll
      for (int j = 2; j < 4; ++j)
#pragma unroll
        for (int kk = 0; kk < 2; ++kk)
          acc[i][j] = __builtin_amdgcn_mfma_f32_16x16x32_bf16(a[i][kk], b[j][kk], acc[i][j], 0, 0, 0);
    __builtin_amdgcn_s_setprio(0);
    if (t < 7) { asm volatile("s_waitcnt vmcnt(0)" ::: "memory"); }
    __builtin_amdgcn_s_barrier();
  }

  // epilogue: row-contiguous store order (j innermost)
  const int r0q = (lane >> 4) * 4, cc = lane & 15;
  const int rowbase = (int)a_row0 + wr * 128;
  const int colbase = (int)b_row0 + wc * 64;
  float bia[4]; bool val[4];
#pragma unroll
  for (int j = 0; j < 4; ++j) {
    int n = colbase + j * 16 + cc;
    val[j] = (n < V_);
    bia[j] = val[j] ? bo[n] : 0.f;
  }
#pragma unroll
  for (int i = 0; i < 8; ++i) {
#pragma unroll
    for (int q = 0; q < 4; ++q) {
      size_t rowoff = (size_t)(rowbase + i * 16 + r0q + q) * V_;
#pragma unroll
      for (int j = 0; j < 4; ++j) {
        if (val[j]) Y[rowoff + colbase + j * 16 + cc] = acc[i][j][q] + bia[j];
      }
    }
  }
}

// ---------------------------------------------------------------------------
// fallback path (ws too small): fp32 Wo reg-staged GEMM + simple prep
// ---------------------------------------------------------------------------
__global__ __launch_bounds__(256) void gemm_out_kernel(
    const bf16* __restrict__ A, const float* __restrict__ Wo,
    const float* __restrict__ bo, float* __restrict__ Y)
{
  __shared__ bf16 As[128 * 64];
  __shared__ bf16 Bs[128 * 64];
  constexpr int K = 512;
  const int tid = threadIdx.x;
  const int wid = tid >> 6, lane = tid & 63;
  const int bm = blockIdx.x, bn = blockIdx.y;
  const int wm = (wid >> 1) * 64, wn = (wid & 1) * 64;
  f32x4 acc[4][4] = {};

  for (int k0 = 0; k0 < K; k0 += 64) {
#pragma unroll
    for (int i = 0; i < 4; ++i) {
      int base = i * 256 + wid * 64;
      int idx = base + lane;
      int row = idx >> 3, col = (idx & 7) << 3;
      gload_lds16(A + ((size_t)bm * 128 + row) * K + (k0 + col), &As[base * 8]);
    }
#pragma unroll
    for (int i = 0; i < 8; ++i) {
      int idx = i * 256 + tid;
      int row = idx >> 4;
      int c4 = (idx & 15) * 4;
      int n = bn * 128 + row;
      int nc = (n < V_) ? n : (V_ - 1);
      f32x4 v = *reinterpret_cast<const f32x4*>(Wo + (size_t)nc * K + k0 + c4);
      bf16x4 t; t[0]=(bf16)v[0]; t[1]=(bf16)v[1]; t[2]=(bf16)v[2]; t[3]=(bf16)v[3];
      *reinterpret_cast<bf16x4*>(&Bs[row * 64 + c4]) = t;
    }
    asm volatile("s_waitcnt vmcnt(0)" ::: "memory");
    __syncthreads();
#pragma unroll
    for (int kk = 0; kk < 2; ++kk) {
      bf16x8 af[4], bb[4];
#pragma unroll
      for (int i = 0; i < 4; ++i)
        af[i] = *reinterpret_cast<const bf16x8*>(
            &As[(wm + i * 16 + (lane & 15)) * 64 + kk * 32 + (lane >> 4) * 8]);
#pragma unroll
      for (int j = 0; j < 4; ++j)
        bb[j] = *reinterpret_cast<const bf16x8*>(
            &Bs[(wn + j * 16 + (lane & 15)) * 64 + kk * 32 + (lane >> 4) * 8]);
#pragma unroll
      for (int i = 0; i < 4; ++i)
#pragma unroll
        for (int j = 0; j < 4; ++j)
          acc[i][j] = __builtin_amdgcn_mfma_f32_16x16x32_bf16(af[i], bb[j], acc[i][j], 0, 0, 0);
    }
    __syncthreads();
  }

  const int r0 = (lane >> 4) * 4, cc = lane & 15;
#pragma unroll
  for (int i = 0; i < 4; ++i)
#pragma unroll
    for (int j = 0; j < 4; ++j) {
      int n = bn * 128 + wn + j * 16 + cc;
      if (n < V_) {
        float bia = bo[n];
#pragma unroll
        for (int q = 0; q < 4; ++q) {
          int mm = bm * 128 + wm + i * 16 + r0 + q;
          Y[(size_t)mm * V_ + n] = acc[i][j][q] + bia;
        }
      }
    }
}

__global__ __launch_bounds__(256) void prep_kernel(
    const float* __restrict__ hprev, const float* __restrict__ x,
    const float* __restrict__ Wz, const float* __restrict__ Wr,
    const float* __restrict__ Wh,
    bf16* __restrict__ gin, bf16* __restrict__ wzrh)
{
  const int i = blockIdx.x * 256 + threadIdx.x;
  constexpr int N1 = B_ * K1_ / 4;
  constexpr int N2 = 1536 * K1_ / 4;
  if (i < N1) {
    int e = i * 4;
    int m = e >> 10, k = e & 1023;
    const float* src = (k < 512) ? (hprev + (size_t)m * 512 + k)
                                 : (x + (size_t)m * 512 + (k - 512));
    f32x4 v = *reinterpret_cast<const f32x4*>(src);
    bf16x4 t; t[0]=(bf16)v[0]; t[1]=(bf16)v[1]; t[2]=(bf16)v[2]; t[3]=(bf16)v[3];
    *reinterpret_cast<bf16x4*>(gin + e) = t;
  } else if (i < N1 + N2) {
    int e = (i - N1) * 4;
    int which = e >> 19;
    int off = e & ((1 << 19) - 1);
    const float* W = (which == 0) ? Wz : (which == 1) ? Wr : Wh;
    f32x4 v = *reinterpret_cast<const f32x4*>(W + off);
    bf16x4 t; t[0]=(bf16)v[0]; t[1]=(bf16)v[1]; t[2]=(bf16)v[2]; t[3]=(bf16)v[3];
    *reinterpret_cast<bf16x4*>(wzrh + e) = t;
  }
}

// ---------------------------------------------------------------------------
extern "C" void kernel_launch(void* const* d_in, const int* in_sizes, int n_in,
                              void* d_out, int out_size, void* d_ws, size_t ws_size,
                              hipStream_t stream) {
  const float* x     = (const float*)d_in[0];
  const float* hprev = (const float*)d_in[1];
  const float* Wz    = (const float*)d_in[2];
  const float* bz    = (const float*)d_in[3];
  const float* gz    = (const float*)d_in[4];
  const float* bez   = (const float*)d_in[5];
  const float* Wr    = (const float*)d_in[6];
  const float* br    = (const float*)d_in[7];
  const float* gr    = (const float*)d_in[8];
  const float* ber   = (const float*)d_in[9];
  const float* Wh    = (const float*)d_in[10];
  const float* bh    = (const float*)d_in[11];
  const float* gh    = (const float*)d_in[12];
  const float* beh   = (const float*)d_in[13];
  const float* Wo    = (const float*)d_in[14];
  const float* bo    = (const float*)d_in[15];

  float* out_h = (float*)d_out;
  float* out_y = out_h + (size_t)B_ * H_;

  char* ws = (char*)d_ws;
  bf16*  gin  = (bf16*)(ws);                      // 4 MB   [2048][1024]
  bf16*  wzrh = (bf16*)(ws + ((size_t)4 << 20));  // 3 MB   [1536][1024]
  float* zrp  = (float*)(ws + ((size_t)7 << 20)); // 8 MB   [2048][1024]
  float* zbuf = (float*)(ws + ((size_t)15 << 20));// 4 MB   [2048][512]
  bf16*  cand = (bf16*)(ws + ((size_t)19 << 20)); // 4 MB   [2048][1024]
  float* hpre = (float*)(ws + ((size_t)23 << 20));// 4 MB   [2048][512]
  bf16*  htb  = (bf16*)(ws + ((size_t)27 << 20)); // 2 MB   [2048][512]
  bf16*  wob  = (bf16*)(ws + ((size_t)29 << 20)); // 51.6 MB [VPAD_][512]

  constexpr size_t NEED = ((size_t)29 << 20) + (size_t)VPAD_ * 512 * 2;

  if (ws_size >= NEED) {
    prep_big_kernel<<<28800, 256, 0, stream>>>(hprev, x, Wz, Wr, Wh, Wo, gin, wzrh, wob);
  } else {
    prep_kernel<<<3584, 256, 0, stream>>>(hprev, x, Wz, Wr, Wh, gin, wzrh);
  }

  gemm_bf16_nt<<<dim3(16, 8), 256, 0, stream>>>(gin, wzrh, zrp, B_, 1024, K1_);
  ln_zr_kernel<<<B_, 256, 0, stream>>>(zrp, bz, br, gz, bez, gr, ber, hprev, x, zbuf, cand);
  gemm_bf16_nt<<<dim3(16, 4), 256, 0, stream>>>(cand, wzrh + (size_t)1024 * 1024, hpre, B_, 512, K1_);
  ln_h_kernel<<<B_, 256, 0, stream>>>(hpre, bh, gh, beh, zbuf, hprev, out_h, htb);

  if (ws_size >= NEED) {
    gemm_out256<<<1576, 512, 0, stream>>>(htb, wob, bo, out_y);
  } else {
    gemm_out_kernel<<<dim3(16, 393), 256, 0, stream>>>(htb, Wo, bo, out_y);
  }
}